// Round 6
// baseline (434.674 us; speedup 1.0000x reference)
//
#include <hip/hip_runtime.h>

// Soft-DTW, gamma=1.0, B=64, N=M=1024, log2-domain DP.
// Pair-representation inside each 4x4 tile (u,s), normalized at tile
// boundaries (7 log2 / 16 cells); see R5. This round: depth-3 register
// prefetch of D (quad buffer, statically unrolled x4) so the HBM latency
// (~900 cyc) is covered by ~3 pipeline steps instead of being exposed
// every step.
//
// Pipeline: 256 threads/block, one block per batch. Thread t owns padded
// rows 4t+1..4t+4; CW=4-column chunks; thread t runs chunk c at step s=t+c
// (511 steps + pad). Bottom-row values -> thread t+1 via double-buffered LDS
// (stride 5 floats). lgkmcnt-only drain before s_barrier keeps global loads
// in flight across barriers.

#define BIGV 1.0e10f
#define LOG2E 1.4426950408889634f
#define LN2 0.6931471805599453f

constexpr int N = 1024;
constexpr int TPB = 256;
constexpr int R = 4;               // rows per thread
constexpr int CW = 4;              // columns per chunk
constexpr int K = N / CW;          // 256 chunks
constexpr int S = TPB + K - 1;     // 511 pipeline steps
constexpr int XW = CW + 1;         // 5-float stride in exchange buffer

__device__ __forceinline__ float fexp2(float x) {
    float r; asm("v_exp_f32 %0, %1" : "=v"(r) : "v"(x)); return r;
}
__device__ __forceinline__ float flog2(float x) {
    float r; asm("v_log_f32 %0, %1" : "=v"(r) : "v"(x)); return r;
}
__device__ __forceinline__ float fmin3(float a, float b, float c) {
    float r; asm("v_min3_f32 %0, %1, %2, %3" : "=v"(r) : "v"(a), "v"(b), "v"(c));
    return r;
}

__global__ __launch_bounds__(TPB)
void softdtw_kernel(const float* __restrict__ D, float* __restrict__ out) {
    const int b = blockIdx.x;
    const int t = threadIdx.x;
    const float* __restrict__ Db = D + (size_t)b * N * N;
    const int i0 = t * R;          // first D row (0-based)

    __shared__ float xch[2][TPB * XW];

    float Lv[R];                   // left boundary values (normalized)
#pragma unroll
    for (int r = 0; r < R; ++r) Lv[r] = BIGV;
    float Cv = (t == 0) ? 0.0f : BIGV;   // top-left corner value

    float dA[R][CW], dB[R][CW], dC[R][CW], dD[R][CW];
    auto PREFETCH = [&](float (&dst)[R][CW], int cn) {
        const float* base = Db + (size_t)i0 * N + cn * CW;
#pragma unroll
        for (int r = 0; r < R; ++r) {
            float4 v = *(const float4*)(base + (size_t)r * N);
            dst[r][0] = v.x; dst[r][1] = v.y; dst[r][2] = v.z; dst[r][3] = v.w;
        }
    };

    int par = 0;

    auto STEP = [&](int s, float (&cur)[R][CW], float (&pfb)[R][CW]) {
        const int cn = s + 3 - t;          // prefetch 3 steps ahead
        if (cn >= 0 && cn < K) PREFETCH(pfb, cn);

        // make prior LDS ops visible; do NOT drain vmcnt (D stays in flight)
        asm volatile("s_waitcnt lgkmcnt(0)" ::: "memory");
        __builtin_amdgcn_s_barrier();
        asm volatile("" ::: "memory");

        const int c = s - t;
        if (c >= 0 && c < K) {
            float Tv[CW + 1];      // top boundary values (normalized)
            Tv[0] = Cv;
            if (t == 0) {
#pragma unroll
                for (int m = 1; m <= CW; ++m) Tv[m] = BIGV;
            } else {
                const float* src = &xch[par][(t - 1) * XW];
#pragma unroll
                for (int m = 1; m <= CW; ++m) Tv[m] = src[m - 1];
            }
            Cv = Tv[CW];           // corner for my next chunk

            float Vu[R][CW], Vs[R][CW];
#pragma unroll
            for (int l = 0; l < R + CW - 1; ++l) {
#pragma unroll
                for (int r = 0; r < R; ++r) {
                    const int m = l - r;
                    if (m >= 0 && m < CW) {
                        const bool aOne = (r == 0) || (m == 0);
                        const bool bOne = (r == 0);
                        const bool cOne = (m == 0);
                        float ua = (r == 0) ? Tv[m]
                                 : ((m == 0) ? Lv[r - 1] : Vu[r - 1][m - 1]);
                        float sa = aOne ? 1.0f : Vs[r - 1][m - 1];
                        float ub = (r == 0) ? Tv[m + 1] : Vu[r - 1][m];
                        float sb = bOne ? 1.0f : Vs[r - 1][m];
                        float uc = (m == 0) ? Lv[r] : Vu[r][m - 1];
                        float sc = cOne ? 1.0f : Vs[r][m - 1];

                        float mn = fmin3(ua, ub, uc);
                        float ea = fexp2(mn - ua);
                        float eb = fexp2(mn - ub);
                        float ec = fexp2(mn - uc);
                        float sig = aOne ? ea : sa * ea;
                        sig = bOne ? (sig + eb) : fmaf(sb, eb, sig);
                        sig = cOne ? (sig + ec) : fmaf(sc, ec, sig);
                        float un = fmaf(cur[r][m], LOG2E, mn);
                        Vu[r][m] = un;
                        Vs[r][m] = sig;

                        // boundary normalization + early export
                        if (r == R - 1 || m == CW - 1) {
                            float vn = un - flog2(sig);
                            if (r == R - 1)
                                xch[par ^ 1][t * XW + m] = vn;
                            if (m == CW - 1)
                                Lv[r] = vn;
                        }
                    }
                }
            }
        }
        par ^= 1;
    };

    // prologue: fill prefetch pipeline for steps 0..2
    {
        int c0 = 0 - t; if (c0 >= 0 && c0 < K) PREFETCH(dA, c0);
        int c1 = 1 - t; if (c1 >= 0 && c1 < K) PREFETCH(dB, c1);
        int c2 = 2 - t; if (c2 >= 0 && c2 < K) PREFETCH(dC, c2);
    }
    for (int s = 0; s < 512; s += 4) {   // covers S=511 steps (+1 pad)
        STEP(s,     dA, dD);
        STEP(s + 1, dB, dA);
        STEP(s + 2, dC, dB);
        STEP(s + 3, dD, dC);
    }

    // R[N][N] = thread 255's Lv[3] (already normalized); unscale from log2
    if (t == TPB - 1) out[b] = Lv[R - 1] * LN2;
}

extern "C" void kernel_launch(void* const* d_in, const int* in_sizes, int n_in,
                              void* d_out, int out_size, void* d_ws, size_t ws_size,
                              hipStream_t stream) {
    const float* D = (const float*)d_in[0];
    float* out = (float*)d_out;
    const int B = in_sizes[0] / (N * N);
    softdtw_kernel<<<B, TPB, 0, stream>>>(D, out);
}